// Round 3
// baseline (127.922 us; speedup 1.0000x reference)
//
#include <hip/hip_runtime.h>

// HashEncoding: 65536 pts x 16 levels, F=16, dense levels 0..5, hash levels 6..15.
// Layout: 4 lanes per (point, level); lane q loads the q-th float4 of each 64-B
// corner entry -> one load instruction covers 16 entries / 16 cache lines.
// R3 changes: (1) nontemporal loads on the hash path (no L1/L2 reuse there;
// repeats are served by the memory-side 256-MB L3 regardless), (2) exact u32
// hash arithmetic replacing 64-bit magic-mod (h < 2^38: fold hi via
// 2^32 mod p = 1019911), (3) hash levels dispatched first, dense last (tail fill).

#define HE_T_PRIME 1048583u
#define HE_R32 1019911u  // 2^32 mod 1048583
typedef float __attribute__((ext_vector_type(4))) f32x4;

static __device__ __constant__ int c_num[16] = {
    16, 22, 30, 42, 58, 80, 110, 152, 210, 290, 400, 553, 763, 1053, 1453, 2005};
// float32(1.0/(num-1)) — matches numpy (1.0/(ENTRIES_NUM-1)).astype(np.float32).
static __device__ __constant__ float c_es[16] = {
    (float)(1.0 / 15.0),   (float)(1.0 / 21.0),   (float)(1.0 / 29.0),
    (float)(1.0 / 41.0),   (float)(1.0 / 57.0),   (float)(1.0 / 79.0),
    (float)(1.0 / 109.0),  (float)(1.0 / 151.0),  (float)(1.0 / 209.0),
    (float)(1.0 / 289.0),  (float)(1.0 / 399.0),  (float)(1.0 / 552.0),
    (float)(1.0 / 762.0),  (float)(1.0 / 1052.0), (float)(1.0 / 1452.0),
    (float)(1.0 / 2004.0)};
// cumulative dense offsets (entries): [0] + cumsum(num^3)[:5]
static __device__ __constant__ int c_doff[6] = {0, 4096, 14744, 41744, 115832, 310944};

__global__ __launch_bounds__(256) void HashEncoding_721554506107_kernel(
    const float* __restrict__ xyz, const float* __restrict__ dense,
    const float* __restrict__ hasht, float* __restrict__ out, int npts) {
  // dispatch hash levels (6..15) first, dense (0..5) last
  const int y = blockIdx.y;
  const int l = (y < 10) ? (y + 6) : (y - 10);
  const int p = blockIdx.x * 64 + (threadIdx.x >> 2);
  const int q = threadIdx.x & 3;  // quarter of the 64-B entry
  if (p >= npts) return;

  const float px = xyz[3 * p + 0];
  const float py = xyz[3 * p + 1];
  const float pz = xyz[3 * p + 2];
  // xn = (x + 2) / 4  (exact power-of-2 divide)
  const float xn0 = (px + 2.0f) * 0.25f;
  const float xn1 = (py + 2.0f) * 0.25f;
  const float xn2 = (pz + 2.0f) * 0.25f;
  if (l == 0 && q < 3) out[19 * p + q] = (q == 0) ? xn0 : ((q == 1) ? xn1 : xn2);

  const int n = c_num[l];
  const float es = c_es[l];
  // IEEE f32 division — must match numpy's xn/es rounding (no fast-math).
  const float fx = xn0 / es;
  const float fy = xn1 / es;
  const float fz = xn2 / es;
  const int nm1 = n - 1;
  // corner-0: trunc(flt) clipped; corner-1: trunc(flt + 1.0f) clipped —
  // the f32 add can round across an integer, reference truncates the SUM.
  const int ix0 = min(max((int)fx, 0), nm1);
  const int iy0 = min(max((int)fy, 0), nm1);
  const int iz0 = min(max((int)fz, 0), nm1);
  const int ix1 = min(max((int)(fx + 1.0f), 0), nm1);
  const int iy1 = min(max((int)(fy + 1.0f), 0), nm1);
  const int iz1 = min(max((int)(fz + 1.0f), 0), nm1);

  const float ox = fx - (float)ix0;
  const float oy = fy - (float)iy0;
  // corner c bits: (x=c>>2, y=(c>>1)&1, z=c&1); weight ignores z: w = wxy[c>>1]
  float wxy[4];
  wxy[0] = (1.0f - ox) * (1.0f - oy);
  wxy[1] = (1.0f - ox) * oy;
  wxy[2] = ox * (1.0f - oy);
  wxy[3] = ox * oy;

  float acc = 0.0f;
  if (l >= 6) {
    const float* tabq =
        hasht + (size_t)(l - 6) * (size_t)(HE_T_PRIME * 16ull) + (size_t)(q * 4);
    // 64-bit hash value h = ix ^ (iy*19349663) ^ (iz*83492791) < 2^38.
    // Split into (hi < 64, lo): XOR decomposes bitwise across words.
    const unsigned yl[2] = {(unsigned)iy0 * 19349663u, (unsigned)iy1 * 19349663u};
    const unsigned yh[2] = {__umulhi((unsigned)iy0, 19349663u),
                            __umulhi((unsigned)iy1, 19349663u)};
    const unsigned zl[2] = {(unsigned)iz0 * 83492791u, (unsigned)iz1 * 83492791u};
    const unsigned zh[2] = {__umulhi((unsigned)iz0, 83492791u),
                            __umulhi((unsigned)iz1, 83492791u)};
    const unsigned xl[2] = {(unsigned)ix0, (unsigned)ix1};
#pragma unroll
    for (int c = 0; c < 8; ++c) {
      const unsigned lo = xl[c >> 2] ^ yl[(c >> 1) & 1] ^ zl[c & 1];
      const unsigned hi = yh[(c >> 1) & 1] ^ zh[c & 1];  // < 64
      // h mod p = (hi * (2^32 mod p) + lo) mod p, exact in u32 with wrap fixup
      const unsigned t = hi * HE_R32;  // < 2^26
      unsigned s = lo + t;
      if (s < lo) s += HE_R32;  // wrapped: +2^32 ≡ +R32 (mod p); no re-wrap
      const unsigned ind = s % HE_T_PRIME;
      const f32x4 v = __builtin_nontemporal_load(
          (const f32x4*)(tabq + (size_t)(ind * 16u)));
      acc = fmaf(wxy[c >> 1], (v.x + v.y) + (v.z + v.w), acc);
    }
  } else {
    const float* tabq = dense + (size_t)(c_doff[l] * 16) + (size_t)(q * 4);
    const unsigned nn = (unsigned)(n * n);
    const unsigned ixs[2] = {(unsigned)ix0 * nn, (unsigned)ix1 * nn};
    const unsigned iys[2] = {(unsigned)(iy0 * n), (unsigned)(iy1 * n)};
    const unsigned izs[2] = {(unsigned)iz0, (unsigned)iz1};
#pragma unroll
    for (int c = 0; c < 8; ++c) {
      const unsigned ind = ixs[c >> 2] + iys[(c >> 1) & 1] + izs[c & 1];
      const f32x4 v = *(const f32x4*)(tabq + (size_t)(ind * 16u));
      acc = fmaf(wxy[c >> 1], (v.x + v.y) + (v.z + v.w), acc);
    }
  }

  // reduce the 4 quarter-sums of this (point, level) quad
  acc += __shfl_xor(acc, 1);
  acc += __shfl_xor(acc, 2);
  if (q == 0) out[19 * p + 3 + l] = acc;
}

extern "C" void kernel_launch(void* const* d_in, const int* in_sizes, int n_in,
                              void* d_out, int out_size, void* d_ws,
                              size_t ws_size, hipStream_t stream) {
  const float* xyz = (const float*)d_in[0];
  const float* dense = (const float*)d_in[1];
  const float* hasht = (const float*)d_in[2];
  float* out = (float*)d_out;
  const int npts = in_sizes[0] / 3;
  dim3 grid((npts + 63) / 64, 16);
  HashEncoding_721554506107_kernel<<<grid, 256, 0, stream>>>(xyz, dense, hasht,
                                                             out, npts);
}

// Round 4
// 117.760 us; speedup vs baseline: 1.0863x; 1.0863x over previous
//
#include <hip/hip_runtime.h>

// HashEncoding: 65536 pts x 16 levels, F=16, dense levels 0..5, hash levels 6..15.
// Layout: 4 lanes per (point, level); lane q loads the q-th float4 of each 64-B
// corner entry -> one load instruction covers 16 entries / 16 cache lines.
// R4: revert R3's nontemporal loads (the ~21% repeat-slot hits need L2/L3
// allocation; nt cost +10us) and revert dispatch order; keep the exact u32
// hash arithmetic (h < 2^38, fold hi word via 2^32 mod p = 1019911).

#define HE_T_PRIME 1048583u
#define HE_R32 1019911u  // 2^32 mod 1048583
typedef float __attribute__((ext_vector_type(4))) f32x4;

static __device__ __constant__ int c_num[16] = {
    16, 22, 30, 42, 58, 80, 110, 152, 210, 290, 400, 553, 763, 1053, 1453, 2005};
// float32(1.0/(num-1)) — matches numpy (1.0/(ENTRIES_NUM-1)).astype(np.float32).
static __device__ __constant__ float c_es[16] = {
    (float)(1.0 / 15.0),   (float)(1.0 / 21.0),   (float)(1.0 / 29.0),
    (float)(1.0 / 41.0),   (float)(1.0 / 57.0),   (float)(1.0 / 79.0),
    (float)(1.0 / 109.0),  (float)(1.0 / 151.0),  (float)(1.0 / 209.0),
    (float)(1.0 / 289.0),  (float)(1.0 / 399.0),  (float)(1.0 / 552.0),
    (float)(1.0 / 762.0),  (float)(1.0 / 1052.0), (float)(1.0 / 1452.0),
    (float)(1.0 / 2004.0)};
// cumulative dense offsets (entries): [0] + cumsum(num^3)[:5]
static __device__ __constant__ int c_doff[6] = {0, 4096, 14744, 41744, 115832, 310944};

__global__ __launch_bounds__(256) void HashEncoding_721554506107_kernel(
    const float* __restrict__ xyz, const float* __restrict__ dense,
    const float* __restrict__ hasht, float* __restrict__ out, int npts) {
  const int l = blockIdx.y;                          // level, uniform per block
  const int p = blockIdx.x * 64 + (threadIdx.x >> 2);
  const int q = threadIdx.x & 3;                     // quarter of the 64-B entry
  if (p >= npts) return;

  const float px = xyz[3 * p + 0];
  const float py = xyz[3 * p + 1];
  const float pz = xyz[3 * p + 2];
  // xn = (x + 2) / 4  (exact power-of-2 divide)
  const float xn0 = (px + 2.0f) * 0.25f;
  const float xn1 = (py + 2.0f) * 0.25f;
  const float xn2 = (pz + 2.0f) * 0.25f;
  if (l == 0 && q < 3) out[19 * p + q] = (q == 0) ? xn0 : ((q == 1) ? xn1 : xn2);

  const int n = c_num[l];
  const float es = c_es[l];
  // IEEE f32 division — must match numpy's xn/es rounding (no fast-math).
  const float fx = xn0 / es;
  const float fy = xn1 / es;
  const float fz = xn2 / es;
  const int nm1 = n - 1;
  // corner-0: trunc(flt) clipped; corner-1: trunc(flt + 1.0f) clipped —
  // the f32 add can round across an integer, reference truncates the SUM.
  const int ix0 = min(max((int)fx, 0), nm1);
  const int iy0 = min(max((int)fy, 0), nm1);
  const int iz0 = min(max((int)fz, 0), nm1);
  const int ix1 = min(max((int)(fx + 1.0f), 0), nm1);
  const int iy1 = min(max((int)(fy + 1.0f), 0), nm1);
  const int iz1 = min(max((int)(fz + 1.0f), 0), nm1);

  const float ox = fx - (float)ix0;
  const float oy = fy - (float)iy0;
  // corner c bits: (x=c>>2, y=(c>>1)&1, z=c&1); weight ignores z: w = wxy[c>>1]
  float wxy[4];
  wxy[0] = (1.0f - ox) * (1.0f - oy);
  wxy[1] = (1.0f - ox) * oy;
  wxy[2] = ox * (1.0f - oy);
  wxy[3] = ox * oy;

  float acc = 0.0f;
  if (l >= 6) {
    const float* tabq =
        hasht + (size_t)(l - 6) * (size_t)(HE_T_PRIME * 16ull) + (size_t)(q * 4);
    // 64-bit hash value h = ix ^ (iy*19349663) ^ (iz*83492791) < 2^38.
    // Split into (hi < 64, lo): XOR decomposes bitwise across words.
    const unsigned yl[2] = {(unsigned)iy0 * 19349663u, (unsigned)iy1 * 19349663u};
    const unsigned yh[2] = {__umulhi((unsigned)iy0, 19349663u),
                            __umulhi((unsigned)iy1, 19349663u)};
    const unsigned zl[2] = {(unsigned)iz0 * 83492791u, (unsigned)iz1 * 83492791u};
    const unsigned zh[2] = {__umulhi((unsigned)iz0, 83492791u),
                            __umulhi((unsigned)iz1, 83492791u)};
    const unsigned xl[2] = {(unsigned)ix0, (unsigned)ix1};
#pragma unroll
    for (int c = 0; c < 8; ++c) {
      const unsigned lo = xl[c >> 2] ^ yl[(c >> 1) & 1] ^ zl[c & 1];
      const unsigned hi = yh[(c >> 1) & 1] ^ zh[c & 1];  // < 64
      // h mod p = (hi * (2^32 mod p) + lo) mod p, exact in u32 with wrap fixup
      const unsigned t = hi * HE_R32;  // < 2^26
      unsigned s = lo + t;
      if (s < lo) s += HE_R32;  // wrapped: +2^32 ≡ +R32 (mod p); no re-wrap
      const unsigned ind = s % HE_T_PRIME;
      const f32x4 v = *(const f32x4*)(tabq + (size_t)(ind * 16u));
      acc = fmaf(wxy[c >> 1], (v.x + v.y) + (v.z + v.w), acc);
    }
  } else {
    const float* tabq = dense + (size_t)(c_doff[l] * 16) + (size_t)(q * 4);
    const unsigned nn = (unsigned)(n * n);
    const unsigned ixs[2] = {(unsigned)ix0 * nn, (unsigned)ix1 * nn};
    const unsigned iys[2] = {(unsigned)(iy0 * n), (unsigned)(iy1 * n)};
    const unsigned izs[2] = {(unsigned)iz0, (unsigned)iz1};
#pragma unroll
    for (int c = 0; c < 8; ++c) {
      const unsigned ind = ixs[c >> 2] + iys[(c >> 1) & 1] + izs[c & 1];
      const f32x4 v = *(const f32x4*)(tabq + (size_t)(ind * 16u));
      acc = fmaf(wxy[c >> 1], (v.x + v.y) + (v.z + v.w), acc);
    }
  }

  // reduce the 4 quarter-sums of this (point, level) quad
  acc += __shfl_xor(acc, 1);
  acc += __shfl_xor(acc, 2);
  if (q == 0) out[19 * p + 3 + l] = acc;
}

extern "C" void kernel_launch(void* const* d_in, const int* in_sizes, int n_in,
                              void* d_out, int out_size, void* d_ws,
                              size_t ws_size, hipStream_t stream) {
  const float* xyz = (const float*)d_in[0];
  const float* dense = (const float*)d_in[1];
  const float* hasht = (const float*)d_in[2];
  float* out = (float*)d_out;
  const int npts = in_sizes[0] / 3;
  dim3 grid((npts + 63) / 64, 16);
  HashEncoding_721554506107_kernel<<<grid, 256, 0, stream>>>(xyz, dense, hasht,
                                                             out, npts);
}

// Round 5
// 115.015 us; speedup vs baseline: 1.1122x; 1.0239x over previous
//
#include <hip/hip_runtime.h>

// HashEncoding: 65536 pts x 16 levels, F=16, dense levels 0..5, hash levels 6..15.
// Layout: 4 lanes per (point, level); lane q loads the q-th float4 of each 64-B
// corner entry -> one load instruction covers 16 entries / 16 cache lines
// (1 line-visit per entry, the minimum for 64-B entries).
// R5 single lever: dispatch hash levels (6..15) FIRST, dense (0..5) last —
// dense L2-resident blocks fill the kernel tail and overlap with the
// HBM-bound hash phase instead of running in a separate cache-only phase.

#define HE_T_PRIME 1048583u
#define HE_R32 1019911u  // 2^32 mod 1048583
typedef float __attribute__((ext_vector_type(4))) f32x4;

static __device__ __constant__ int c_num[16] = {
    16, 22, 30, 42, 58, 80, 110, 152, 210, 290, 400, 553, 763, 1053, 1453, 2005};
// float32(1.0/(num-1)) — matches numpy (1.0/(ENTRIES_NUM-1)).astype(np.float32).
static __device__ __constant__ float c_es[16] = {
    (float)(1.0 / 15.0),   (float)(1.0 / 21.0),   (float)(1.0 / 29.0),
    (float)(1.0 / 41.0),   (float)(1.0 / 57.0),   (float)(1.0 / 79.0),
    (float)(1.0 / 109.0),  (float)(1.0 / 151.0),  (float)(1.0 / 209.0),
    (float)(1.0 / 289.0),  (float)(1.0 / 399.0),  (float)(1.0 / 552.0),
    (float)(1.0 / 762.0),  (float)(1.0 / 1052.0), (float)(1.0 / 1452.0),
    (float)(1.0 / 2004.0)};
// cumulative dense offsets (entries): [0] + cumsum(num^3)[:5]
static __device__ __constant__ int c_doff[6] = {0, 4096, 14744, 41744, 115832, 310944};

__global__ __launch_bounds__(256) void HashEncoding_721554506107_kernel(
    const float* __restrict__ xyz, const float* __restrict__ dense,
    const float* __restrict__ hasht, float* __restrict__ out, int npts) {
  // hash levels first (y=0..9 -> l=6..15), dense last (y=10..15 -> l=0..5)
  const int y = blockIdx.y;
  const int l = (y < 10) ? (y + 6) : (y - 10);
  const int p = blockIdx.x * 64 + (threadIdx.x >> 2);
  const int q = threadIdx.x & 3;  // quarter of the 64-B entry
  if (p >= npts) return;

  const float px = xyz[3 * p + 0];
  const float py = xyz[3 * p + 1];
  const float pz = xyz[3 * p + 2];
  // xn = (x + 2) / 4  (exact power-of-2 divide)
  const float xn0 = (px + 2.0f) * 0.25f;
  const float xn1 = (py + 2.0f) * 0.25f;
  const float xn2 = (pz + 2.0f) * 0.25f;
  if (l == 0 && q < 3) out[19 * p + q] = (q == 0) ? xn0 : ((q == 1) ? xn1 : xn2);

  const int n = c_num[l];
  const float es = c_es[l];
  // IEEE f32 division — must match numpy's xn/es rounding (no fast-math).
  const float fx = xn0 / es;
  const float fy = xn1 / es;
  const float fz = xn2 / es;
  const int nm1 = n - 1;
  // corner-0: trunc(flt) clipped; corner-1: trunc(flt + 1.0f) clipped —
  // the f32 add can round across an integer, reference truncates the SUM.
  const int ix0 = min(max((int)fx, 0), nm1);
  const int iy0 = min(max((int)fy, 0), nm1);
  const int iz0 = min(max((int)fz, 0), nm1);
  const int ix1 = min(max((int)(fx + 1.0f), 0), nm1);
  const int iy1 = min(max((int)(fy + 1.0f), 0), nm1);
  const int iz1 = min(max((int)(fz + 1.0f), 0), nm1);

  const float ox = fx - (float)ix0;
  const float oy = fy - (float)iy0;
  // corner c bits: (x=c>>2, y=(c>>1)&1, z=c&1); weight ignores z: w = wxy[c>>1]
  float wxy[4];
  wxy[0] = (1.0f - ox) * (1.0f - oy);
  wxy[1] = (1.0f - ox) * oy;
  wxy[2] = ox * (1.0f - oy);
  wxy[3] = ox * oy;

  float acc = 0.0f;
  if (l >= 6) {
    const float* tabq =
        hasht + (size_t)(l - 6) * (size_t)(HE_T_PRIME * 16ull) + (size_t)(q * 4);
    // 64-bit hash value h = ix ^ (iy*19349663) ^ (iz*83492791) < 2^38.
    // Split into (hi < 64, lo): XOR decomposes bitwise across words.
    const unsigned yl[2] = {(unsigned)iy0 * 19349663u, (unsigned)iy1 * 19349663u};
    const unsigned yh[2] = {__umulhi((unsigned)iy0, 19349663u),
                            __umulhi((unsigned)iy1, 19349663u)};
    const unsigned zl[2] = {(unsigned)iz0 * 83492791u, (unsigned)iz1 * 83492791u};
    const unsigned zh[2] = {__umulhi((unsigned)iz0, 83492791u),
                            __umulhi((unsigned)iz1, 83492791u)};
    const unsigned xl[2] = {(unsigned)ix0, (unsigned)ix1};
#pragma unroll
    for (int c = 0; c < 8; ++c) {
      const unsigned lo = xl[c >> 2] ^ yl[(c >> 1) & 1] ^ zl[c & 1];
      const unsigned hi = yh[(c >> 1) & 1] ^ zh[c & 1];  // < 64
      // h mod p = (hi * (2^32 mod p) + lo) mod p, exact in u32 with wrap fixup
      const unsigned t = hi * HE_R32;  // < 2^26
      unsigned s = lo + t;
      if (s < lo) s += HE_R32;  // wrapped: +2^32 ≡ +R32 (mod p); no re-wrap
      const unsigned ind = s % HE_T_PRIME;
      const f32x4 v = *(const f32x4*)(tabq + (size_t)(ind * 16u));
      acc = fmaf(wxy[c >> 1], (v.x + v.y) + (v.z + v.w), acc);
    }
  } else {
    const float* tabq = dense + (size_t)(c_doff[l] * 16) + (size_t)(q * 4);
    const unsigned nn = (unsigned)(n * n);
    const unsigned ixs[2] = {(unsigned)ix0 * nn, (unsigned)ix1 * nn};
    const unsigned iys[2] = {(unsigned)(iy0 * n), (unsigned)(iy1 * n)};
    const unsigned izs[2] = {(unsigned)iz0, (unsigned)iz1};
#pragma unroll
    for (int c = 0; c < 8; ++c) {
      const unsigned ind = ixs[c >> 2] + iys[(c >> 1) & 1] + izs[c & 1];
      const f32x4 v = *(const f32x4*)(tabq + (size_t)(ind * 16u));
      acc = fmaf(wxy[c >> 1], (v.x + v.y) + (v.z + v.w), acc);
    }
  }

  // reduce the 4 quarter-sums of this (point, level) quad
  acc += __shfl_xor(acc, 1);
  acc += __shfl_xor(acc, 2);
  if (q == 0) out[19 * p + 3 + l] = acc;
}

extern "C" void kernel_launch(void* const* d_in, const int* in_sizes, int n_in,
                              void* d_out, int out_size, void* d_ws,
                              size_t ws_size, hipStream_t stream) {
  const float* xyz = (const float*)d_in[0];
  const float* dense = (const float*)d_in[1];
  const float* hasht = (const float*)d_in[2];
  float* out = (float*)d_out;
  const int npts = in_sizes[0] / 3;
  dim3 grid((npts + 63) / 64, 16);
  HashEncoding_721554506107_kernel<<<grid, 256, 0, stream>>>(xyz, dense, hasht,
                                                             out, npts);
}